// Round 6
// baseline (601.693 us; speedup 1.0000x reference)
//
#include <hip/hip_runtime.h>
#include <cstdint>
#include <cstddef>

// Problem constants (from reference: B=2, P=8192, K=20)
#define PBUF 8192
#define NZB 256            // z bins
#define NYB 32             // y bins within each z bin (lexicographic sort key)
#define NBINS (NZB * NYB)  // 8192 flat bins per combo
#define NCOMBO 4           // (side, batch) combos: c = side*2 + b
#define KNN 20
#define CAP 256            // survivor cap per query (expected <=130)

// binning: transformed coords bounded by ~|v|<=64; [-72,72] covers all
#define ZMIN_F (-72.0f)
#define INV_BINW (256.0f / 144.0f)
#define INV_YBINW (32.0f / 144.0f)

#define IDX_MASK 0x1FFFu
#define D2_MASK 0xFFFFE000u
#define KEY_INF 0xFFFFFFFFu

// eps-filter: terms with d2 > 21*ls contribute < 2exp(-21) each; worst-case induced
// output error <= 2exp(-21) ~ 1.5e-9 << 1.69e-8 abs threshold (ref value ~8.5e-7).
#define THR_MULT 21.0f

// workspace layout (bytes)
#define OFF_ACCUM   0                                       // 512 floats: [side][256 cells]
#define OFF_CNT     2048                                    // 1 uint completion counter
#define OFF_DBSTART 2064                                    // 4 * 8193 ints (flat (z,y) prefix)
#define OFF_DBPOS   133152                                  // 16-aligned
#define ARR_BYTES   (NCOMBO * PBUF * 16)                    // 524288 per float4 array
#define OFF_DBF1    (OFF_DBPOS + ARR_BYTES)
#define OFF_DBF2    (OFF_DBF1 + ARR_BYTES)
// total ws use ~1.71 MB

__device__ __forceinline__ int binOfZ(float z) {
  int b = (int)floorf((z - ZMIN_F) * INV_BINW);
  return min(max(b, 0), NZB - 1);
}
__device__ __forceinline__ int binOfY(float y) {
  int b = (int)floorf((y - ZMIN_F) * INV_YBINW);
  return min(max(b, 0), NYB - 1);
}

__device__ __forceinline__ float xformRow(const float* R, float tr, float x0, float x1, float x2) {
  return __fmaf_rn(R[2], x2, __fmaf_rn(R[1], x1, __fmaf_rn(R[0], x0, tr)));
}

// ---------------- K_build: count + prefix + scatter in ONE kernel (1 block per combo, LDS bins) ----
__global__ __launch_bounds__(1024) void k_build(
    const float* xyz1, const float* xyz2,
    const float* hsv1, const float* hsv2,
    const float* normal1, const float* normal2,
    const float* nres1, const float* nres2,
    const float* R12, const float* t12,
    const float* R21, const float* t21,
    const int* npts1, const int* npts2, char* ws) {
  __shared__ int bins[NBINS];     // 32 KB: counts -> starts/cursors
  __shared__ int wsum[17];
  const int t = threadIdx.x;
  const int lane = t & 63, wv = t >> 6;
  const int c = blockIdx.x;
  const int s = c >> 1, b = c & 1;

  // block 0 zeroes the accumulator cells + completion counter (poisoned 0xAA each call)
  if (c == 0) {
    if (t < 512) ((float*)(ws + OFF_ACCUM))[t] = 0.f;
    if (t == 512) *(unsigned*)(ws + OFF_CNT) = 0u;
  }

  const float* dsrc = s == 0 ? xyz2 : xyz1;
  const float* dh = s == 0 ? hsv2 : hsv1;
  const float* dn = s == 0 ? normal2 : normal1;
  const float* dr = s == 0 ? nres2 : nres1;
  const float* R  = (s == 0 ? R12 : R21) + b * 9;
  const float* tt = (s == 0 ? t12 : t21) + b * 3;
  const int ldb = (s == 0 ? npts2 : npts1)[b];
  const float R3 = R[3], R4 = R[4], R5 = R[5], R6 = R[6], R7 = R[7], R8 = R[8];
  const float R0 = R[0], R1 = R[1], R2 = R[2];
  const float t0 = tt[0], t1 = tt[1], t2 = tt[2];

  // zero bins
  #pragma unroll
  for (int k = 0; k < 8; ++k) bins[t + k * 1024] = 0;
  __syncthreads();

  // count
  for (int j = t; j < ldb; j += 1024) {
    const float* x = dsrc + (size_t)(b * PBUF + j) * 3;
    float x0 = x[0], x1 = x[1], x2 = x[2];
    float y1 = __fmaf_rn(R5, x2, __fmaf_rn(R4, x1, __fmaf_rn(R3, x0, t1)));
    float y2 = __fmaf_rn(R8, x2, __fmaf_rn(R7, x1, __fmaf_rn(R6, x0, t2)));
    atomicAdd(&bins[binOfZ(y2) * NYB + binOfY(y1)], 1);
  }
  __syncthreads();

  // prefix over 8192 bins (8 per thread, wave scan + cross-wave scan)
  int* st = (int*)(ws + OFF_DBSTART) + c * (NBINS + 1);
  {
    int base = t * 8;
    int v[8];
    int sum = 0;
    #pragma unroll
    for (int k = 0; k < 8; ++k) { v[k] = bins[base + k]; sum += v[k]; }
    int incl = sum;
    #pragma unroll
    for (int o = 1; o < 64; o <<= 1) {
      int n = __shfl_up(incl, o);
      if (lane >= o) incl += n;
    }
    if (lane == 63) wsum[wv] = incl;
    __syncthreads();
    if (t == 0) {
      int r = 0;
      #pragma unroll
      for (int w = 0; w < 16; ++w) { int x = wsum[w]; wsum[w] = r; r += x; }
      wsum[16] = r;
    }
    __syncthreads();
    int run = wsum[wv] + incl - sum;   // exclusive prefix for this thread's chunk
    #pragma unroll
    for (int k = 0; k < 8; ++k) {
      st[base + k] = run;
      v[k] = run + v[k];               // next cursor value after my own writes? no: store start
      run = v[k];
    }
    // rewrite bins as cursors (= starts)
    int run2 = wsum[wv] + incl - sum;
    #pragma unroll
    for (int k = 0; k < 8; ++k) {
      int tmp = bins[base + k];        // original count
      bins[base + k] = run2;
      run2 += tmp;
    }
    if (t == 1023) st[NBINS] = wsum[16];
  }
  __syncthreads();

  // scatter
  float4* dbPos = (float4*)(ws + OFF_DBPOS) + c * PBUF;
  float4* dbF1  = (float4*)(ws + OFF_DBF1) + c * PBUF;
  float4* dbF2  = (float4*)(ws + OFF_DBF2) + c * PBUF;
  for (int j = t; j < ldb; j += 1024) {
    size_t pj = (size_t)(b * PBUF + j);
    const float* x = dsrc + pj * 3;
    float x0 = x[0], x1 = x[1], x2 = x[2];
    float y0 = __fmaf_rn(R2, x2, __fmaf_rn(R1, x1, __fmaf_rn(R0, x0, t0)));
    float y1 = __fmaf_rn(R5, x2, __fmaf_rn(R4, x1, __fmaf_rn(R3, x0, t1)));
    float y2 = __fmaf_rn(R8, x2, __fmaf_rn(R7, x1, __fmaf_rn(R6, x0, t2)));
    const float* n = dn + pj * 3;
    float nx = n[0], ny = n[1], nz = n[2];
    float n0 = __fmaf_rn(R2, nz, __fmaf_rn(R1, ny, R0 * nx));
    float n1 = __fmaf_rn(R5, nz, __fmaf_rn(R4, ny, R3 * nx));
    float n2 = __fmaf_rn(R8, nz, __fmaf_rn(R7, ny, R6 * nx));
    const float* h = dh + pj * 3;
    float r = dr[pj];
    int bin = binOfZ(y2) * NYB + binOfY(y1);
    int pos = atomicAdd(&bins[bin], 1);
    dbPos[pos] = make_float4(y0, y1, y2, 0.f);
    dbF1[pos] = make_float4(h[0], h[1], h[2], r);   // hsv, nres
    dbF2[pos] = make_float4(n0, n1, n2, 0.f);       // normal
  }
}

// ---------------- K_main: 1 wave/query; (z,y)-window segment walk + fused finalize ----------------
__global__ __launch_bounds__(256) void k_main(
    const float* xyz1, const float* xyz2,
    const float* hsv1, const float* hsv2,
    const float* normal1, const float* normal2,
    const float* nres1, const float* nres2,
    const int* npts1, const int* npts2, char* ws, float* out) {
  __shared__ unsigned sBuf[4 * CAP];
  __shared__ float sRed[8];
  __shared__ int sLast;
  const int tid = threadIdx.x;
  const int lane = tid & 63;
  const int wIn = tid >> 6;
  const int gw = blockIdx.x * 4 + wIn;              // 0..32767
  const int c = gw >> 13;
  const int qi = (int)(__brev((unsigned)(gw & 8191)) >> 19);  // bit-reversed: load balance
  const int s = c >> 1, b = c & 1;
  const int lq = (s == 0 ? npts1 : npts2)[b];

  if (qi < lq) {                                    // wave-uniform predicate (no early return: fused final)
    const size_t qo = (size_t)(b * PBUF + qi);
    const float* qx = (s == 0 ? xyz1 : xyz2) + qo * 3;
    const float* qh = (s == 0 ? hsv1 : hsv2) + qo * 3;
    const float* qn = (s == 0 ? normal1 : normal2) + qo * 3;
    const float* qr = (s == 0 ? nres1 : nres2) + qo;
    const float qpx = qx[0], qpy = qx[1], qpz = qx[2];
    const float qh0 = qh[0], qh1 = qh[1], qh2 = qh[2];
    const float qn0 = qn[0], qn1 = qn[1], qn2 = qn[2];
    const float qres = qr[0];

    const float ell = fmaxf(0.015f * (qpz - 10.0f), 0.15f);
    const float ls = ell * ell;
    const float thrF = THR_MULT * ls;
    const float rad = sqrtf(thrF);

    const int* F = (const int*)(ws + OFF_DBSTART) + c * (NBINS + 1);
    const int zlo = binOfZ(qpz - rad), zhi = binOfZ(qpz + rad);
    const int ylo = binOfY(qpy - rad), yhi = binOfY(qpy + rad);
    const int nseg = zhi - zlo + 1;                 // <= 14

    int segS = 0, segLen = 0;
    if (lane < nseg) {
      int zk = zlo + lane;
      segS = F[zk * NYB + ylo];
      segLen = F[zk * NYB + yhi + 1] - segS;        // yhi=31 rolls into next z-bin start: correct
    }
    int cum = segLen;
    #pragma unroll
    for (int o = 1; o < 64; o <<= 1) {
      int n = __shfl_up(cum, o);
      if (lane >= o) cum += n;
    }
    const int L = __shfl(cum, 63);
    const int excl = cum - segLen;

    const float4* dbPos = (const float4*)(ws + OFF_DBPOS) + c * PBUF;
    const float4* dbF1  = (const float4*)(ws + OFF_DBF1) + c * PBUF;
    const float4* dbF2  = (const float4*)(ws + OFF_DBF2) + c * PBUF;

    unsigned* buf = sBuf + wIn * CAP;
    int pos = 0;
    for (int base = 0; base < L; base += 64) {
      int t = base + lane;
      bool in = t < L;
      int tc = min(t, L - 1);
      int kk = 0;                                   // binary search: largest k with excl[k] <= tc
      #pragma unroll
      for (int step = 8; step; step >>= 1) {
        int cnd = kk + step;
        int e = __shfl(excl, cnd & 63);
        if (cnd < nseg && e <= tc) kk = cnd;
      }
      int j = __shfl(segS, kk) + (tc - __shfl(excl, kk));
      float4 p = dbPos[j];
      float dx = p.x - qpx, dy = p.y - qpy, dz = p.z - qpz;
      float d2 = __fmaf_rn(dx, dx, __fmaf_rn(dy, dy, dz * dz));
      bool keep = in && (d2 <= thrF);
      unsigned long long m = __ballot(keep);
      int rank = (int)__popcll(m & ((1ull << lane) - 1ull));
      if (keep) {
        int pidx = pos + rank;
        if (pidx < CAP) buf[pidx] = (__float_as_uint(d2) & D2_MASK) | (unsigned)j;
      }
      pos += (int)__popcll(m);
    }
    pos = min(pos, CAP);

    // select top-KNN survivors; deposit r-th smallest on lane r
    unsigned key = KEY_INF;
    if (pos <= KNN) {
      if (lane < pos) key = buf[lane];              // all survive: selection is identity
    } else if (pos <= 64) {
      unsigned v = (lane < pos) ? buf[lane] : KEY_INF;
      #pragma unroll
      for (int k = 2; k <= 64; k <<= 1) {
        #pragma unroll
        for (int j2 = k >> 1; j2 > 0; j2 >>= 1) {
          unsigned o = __shfl_xor(v, j2);
          bool up = (lane & k) == 0;
          bool lowhalf = (lane & j2) == 0;
          v = (lowhalf == up) ? min(v, o) : max(v, o);
        }
      }
      key = v;                                      // ascending across lanes
    } else {
      unsigned r0 = (lane < pos) ? buf[lane] : KEY_INF;
      unsigned r1 = (lane + 64 < pos) ? buf[lane + 64] : KEY_INF;
      unsigned r2 = (lane + 128 < pos) ? buf[lane + 128] : KEY_INF;
      unsigned r3 = (lane + 192 < pos) ? buf[lane + 192] : KEY_INF;
      { unsigned lo, hi;
        lo = min(r0, r1); hi = max(r0, r1); r0 = lo; r1 = hi;
        lo = min(r2, r3); hi = max(r2, r3); r2 = lo; r3 = hi;
        lo = min(r0, r2); hi = max(r0, r2); r0 = lo; r2 = hi;
        lo = min(r1, r3); hi = max(r1, r3); r1 = lo; r3 = hi;
        lo = min(r1, r2); hi = max(r1, r2); r1 = lo; r2 = hi; }
      unsigned kout = KEY_INF;
      #pragma unroll
      for (int t = 0; t < KNN; ++t) {
        unsigned m0 = r0;
        m0 = min(m0, __shfl_xor(m0, 1));
        m0 = min(m0, __shfl_xor(m0, 2));
        m0 = min(m0, __shfl_xor(m0, 4));
        m0 = min(m0, __shfl_xor(m0, 8));
        m0 = min(m0, __shfl_xor(m0, 16));
        m0 = min(m0, __shfl_xor(m0, 32));
        unsigned long long bal = __ballot(r0 == m0);
        int owner = __ffsll(bal) - 1;               // keys unique (idx embedded)
        if (lane == owner) { r0 = r1; r1 = r2; r2 = r3; r3 = KEY_INF; }
        if (lane == t) kout = m0;
      }
      key = kout;
    }

    // evaluate: lanes 0..19 each handle one selected neighbor
    float lsum = 0.f;
    if (lane < KNN && key != KEY_INF) {
      int j = (int)(key & IDX_MASK);
      float4 p = dbPos[j];
      float4 f1 = dbF1[j];
      float4 f2 = dbF2[j];
      float dx = p.x - qpx, dy = p.y - qpy, dz = p.z - qpz;
      float d2 = __fmaf_rn(dx, dx, __fmaf_rn(dy, dy, dz * dz));   // exact d2
      float inv_ls = 1.0f / ls;
      float dist_k = __expf(-d2 * inv_ls);
      float c0 = qh0 - f1.x, c1 = qh1 - f1.y, c2 = qh2 - f1.z;
      float cd = sqrtf(__fmaf_rn(c0, c0, __fmaf_rn(c1, c1, c2 * c2)) + 1e-12f);
      float color_k = __expf(cd * -5.0f);
      float alpha = 0.2f / (0.1f + qres + f1.w);
      float nd = __fmaf_rn(qn0, f2.x, __fmaf_rn(qn1, f2.y, qn2 * f2.z));
      float nk = fmaxf(nd * alpha, 0.0f);
      lsum = dist_k * color_k * nk;
    }
    #pragma unroll
    for (int o = 32; o; o >>= 1) lsum += __shfl_down(lsum, o);
    if (lane == 0)
      atomicAdd((float*)(ws + OFF_ACCUM) + (s * 256 + (blockIdx.x & 255)), lsum);
  }

  // ---- fused finalize: last block to finish reduces the 512 cells ----
  __threadfence();
  __syncthreads();
  if (tid == 0) {
    unsigned old = atomicAdd((unsigned*)(ws + OFF_CNT), 1u);
    sLast = (old == (unsigned)(gridDim.x - 1)) ? 1 : 0;
  }
  __syncthreads();
  if (sLast) {
    float* acc = (float*)(ws + OFF_ACCUM);
    float v1 = atomicAdd(acc + tid, 0.f);           // coherent read (device-scope)
    float v2 = atomicAdd(acc + 256 + tid, 0.f);
    #pragma unroll
    for (int o = 32; o; o >>= 1) {
      v1 += __shfl_down(v1, o);
      v2 += __shfl_down(v2, o);
    }
    if (lane == 0) { sRed[wIn] = v1; sRed[4 + wIn] = v2; }
    __syncthreads();
    if (tid == 0) {
      float s1 = sRed[0] + sRed[1] + sRed[2] + sRed[3];
      float s2 = sRed[4] + sRed[5] + sRed[6] + sRed[7];
      float k1 = s1 / (20.0f * (float)(npts1[0] + npts1[1]));
      float k2 = s2 / (20.0f * (float)(npts2[0] + npts2[1]));
      out[0] = 0.5f * (k1 + k2);
    }
  }
}

extern "C" void kernel_launch(void* const* d_in, const int* in_sizes, int n_in,
                              void* d_out, int out_size, void* d_ws, size_t ws_size,
                              hipStream_t stream) {
  const float* xyz1 = (const float*)d_in[0];
  const float* xyz2 = (const float*)d_in[1];
  const float* hsv1 = (const float*)d_in[2];
  const float* hsv2 = (const float*)d_in[3];
  const float* normal1 = (const float*)d_in[4];
  const float* normal2 = (const float*)d_in[5];
  const float* nres1 = (const float*)d_in[6];
  const float* nres2 = (const float*)d_in[7];
  const float* R12 = (const float*)d_in[8];
  const float* t12 = (const float*)d_in[9];
  const float* R21 = (const float*)d_in[10];
  const float* t21 = (const float*)d_in[11];
  const int* npts1 = (const int*)d_in[12];
  const int* npts2 = (const int*)d_in[13];
  char* ws = (char*)d_ws;
  float* out = (float*)d_out;

  k_build<<<dim3(NCOMBO), dim3(1024), 0, stream>>>(
      xyz1, xyz2, hsv1, hsv2, normal1, normal2, nres1, nres2,
      R12, t12, R21, t21, npts1, npts2, ws);
  k_main<<<dim3(NCOMBO * PBUF / 4), dim3(256), 0, stream>>>(
      xyz1, xyz2, hsv1, hsv2, normal1, normal2, nres1, nres2, npts1, npts2, ws, out);
}

// Round 7
// 137.683 us; speedup vs baseline: 4.3701x; 4.3701x over previous
//
#include <hip/hip_runtime.h>
#include <cstdint>
#include <cstddef>

// Problem constants (from reference: B=2, P=8192, K=20)
#define PBUF 8192
#define NZB 256            // z bins
#define NYB 32             // y bins within each z bin (lexicographic sort key)
#define NBINS (NZB * NYB)  // 8192 flat bins per combo
#define NCOMBO 4           // (side, batch) combos: c = side*2 + b
#define KNN 20
#define CAP 256            // survivor cap per query (expected <=130)

// binning: transformed coords bounded by ~|v|<=64; [-72,72] covers all
#define ZMIN_F (-72.0f)
#define INV_BINW (256.0f / 144.0f)
#define INV_YBINW (32.0f / 144.0f)

#define IDX_MASK 0x1FFFu
#define D2_MASK 0xFFFFE000u
#define KEY_INF 0xFFFFFFFFu

// eps-filter: terms with d2 > 21*ls contribute < 2exp(-21) each; worst-case induced
// output error <= ~1.5e-9 << 1.69e-8 abs threshold (ref value ~8.5e-7).
#define THR_MULT 21.0f

// workspace layout (bytes)
#define OFF_ACCUM   0                                       // 512 floats: [side][256 cells]
#define OFF_DBSTART 2064                                    // 4 * 8193 ints (flat (z,y) prefix)
#define OFF_DBPOS   133152                                  // 16-aligned
#define ARR_BYTES   (NCOMBO * PBUF * 16)                    // 524288 per float4 array
#define OFF_DBF1    (OFF_DBPOS + ARR_BYTES)
#define OFF_DBF2    (OFF_DBF1 + ARR_BYTES)
// total ws use ~1.71 MB

__device__ __forceinline__ int binOfZ(float z) {
  int b = (int)floorf((z - ZMIN_F) * INV_BINW);
  return min(max(b, 0), NZB - 1);
}
__device__ __forceinline__ int binOfY(float y) {
  int b = (int)floorf((y - ZMIN_F) * INV_YBINW);
  return min(max(b, 0), NYB - 1);
}

// ---------------- K_build: count + prefix + scatter in ONE kernel (1 block per combo, LDS bins) ----
// NOTE (R6 post-mortem): do NOT fuse finalize into k_main via per-block __threadfence —
// device-scope fences force L2 writeback on gfx950 and cost ~500 µs across 8k blocks.
__global__ __launch_bounds__(1024) void k_build(
    const float* xyz1, const float* xyz2,
    const float* hsv1, const float* hsv2,
    const float* normal1, const float* normal2,
    const float* nres1, const float* nres2,
    const float* R12, const float* t12,
    const float* R21, const float* t21,
    const int* npts1, const int* npts2, char* ws) {
  __shared__ int bins[NBINS];     // 32 KB: counts -> starts/cursors
  __shared__ int wsum[17];
  const int t = threadIdx.x;
  const int lane = t & 63, wv = t >> 6;
  const int c = blockIdx.x;
  const int s = c >> 1, b = c & 1;

  // block 0 zeroes the accumulator cells (ws is poisoned 0xAA before every call)
  if (c == 0 && t < 512) ((float*)(ws + OFF_ACCUM))[t] = 0.f;

  const float* dsrc = s == 0 ? xyz2 : xyz1;
  const float* dh = s == 0 ? hsv2 : hsv1;
  const float* dn = s == 0 ? normal2 : normal1;
  const float* dr = s == 0 ? nres2 : nres1;
  const float* R  = (s == 0 ? R12 : R21) + b * 9;
  const float* tt = (s == 0 ? t12 : t21) + b * 3;
  const int ldb = (s == 0 ? npts2 : npts1)[b];
  const float R0 = R[0], R1 = R[1], R2 = R[2];
  const float R3 = R[3], R4 = R[4], R5 = R[5], R6 = R[6], R7 = R[7], R8 = R[8];
  const float t0 = tt[0], t1 = tt[1], t2 = tt[2];

  // zero bins
  #pragma unroll
  for (int k = 0; k < 8; ++k) bins[t + k * 1024] = 0;
  __syncthreads();

  // count
  for (int j = t; j < ldb; j += 1024) {
    const float* x = dsrc + (size_t)(b * PBUF + j) * 3;
    float x0 = x[0], x1 = x[1], x2 = x[2];
    float y1 = __fmaf_rn(R5, x2, __fmaf_rn(R4, x1, __fmaf_rn(R3, x0, t1)));
    float y2 = __fmaf_rn(R8, x2, __fmaf_rn(R7, x1, __fmaf_rn(R6, x0, t2)));
    atomicAdd(&bins[binOfZ(y2) * NYB + binOfY(y1)], 1);
  }
  __syncthreads();

  // prefix over 8192 bins (8 per thread, wave scan + cross-wave scan)
  int* st = (int*)(ws + OFF_DBSTART) + c * (NBINS + 1);
  {
    int base = t * 8;
    int v[8];
    int sum = 0;
    #pragma unroll
    for (int k = 0; k < 8; ++k) { v[k] = bins[base + k]; sum += v[k]; }
    int incl = sum;
    #pragma unroll
    for (int o = 1; o < 64; o <<= 1) {
      int n = __shfl_up(incl, o);
      if (lane >= o) incl += n;
    }
    if (lane == 63) wsum[wv] = incl;
    __syncthreads();
    if (t == 0) {
      int r = 0;
      #pragma unroll
      for (int w = 0; w < 16; ++w) { int x = wsum[w]; wsum[w] = r; r += x; }
      wsum[16] = r;
    }
    __syncthreads();
    int run = wsum[wv] + incl - sum;   // exclusive prefix for this thread's chunk
    #pragma unroll
    for (int k = 0; k < 8; ++k) {
      int cntk = v[k];
      st[base + k] = run;
      v[k] = run;                      // stash start for cursor rewrite
      run += cntk;
    }
    __syncthreads();                   // all reads of bins[] (counts) done before rewrite
    #pragma unroll
    for (int k = 0; k < 8; ++k) bins[base + k] = v[k];   // cursors = starts
    if (t == 1023) st[NBINS] = run;
  }
  __syncthreads();

  // scatter
  float4* dbPos = (float4*)(ws + OFF_DBPOS) + c * PBUF;
  float4* dbF1  = (float4*)(ws + OFF_DBF1) + c * PBUF;
  float4* dbF2  = (float4*)(ws + OFF_DBF2) + c * PBUF;
  for (int j = t; j < ldb; j += 1024) {
    size_t pj = (size_t)(b * PBUF + j);
    const float* x = dsrc + pj * 3;
    float x0 = x[0], x1 = x[1], x2 = x[2];
    float y0 = __fmaf_rn(R2, x2, __fmaf_rn(R1, x1, __fmaf_rn(R0, x0, t0)));
    float y1 = __fmaf_rn(R5, x2, __fmaf_rn(R4, x1, __fmaf_rn(R3, x0, t1)));
    float y2 = __fmaf_rn(R8, x2, __fmaf_rn(R7, x1, __fmaf_rn(R6, x0, t2)));
    const float* n = dn + pj * 3;
    float nx = n[0], ny = n[1], nz = n[2];
    float n0 = __fmaf_rn(R2, nz, __fmaf_rn(R1, ny, R0 * nx));
    float n1 = __fmaf_rn(R5, nz, __fmaf_rn(R4, ny, R3 * nx));
    float n2 = __fmaf_rn(R8, nz, __fmaf_rn(R7, ny, R6 * nx));
    const float* h = dh + pj * 3;
    float r = dr[pj];
    int bin = binOfZ(y2) * NYB + binOfY(y1);
    int pos = atomicAdd(&bins[bin], 1);
    dbPos[pos] = make_float4(y0, y1, y2, 0.f);
    dbF1[pos] = make_float4(h[0], h[1], h[2], r);   // hsv, nres
    dbF2[pos] = make_float4(n0, n1, n2, 0.f);       // normal
  }
}

// ---------------- K_main: 1 wave/query; (z,y)-window segment walk + ballot compaction ----------------
__global__ __launch_bounds__(256) void k_main(
    const float* xyz1, const float* xyz2,
    const float* hsv1, const float* hsv2,
    const float* normal1, const float* normal2,
    const float* nres1, const float* nres2,
    const int* npts1, const int* npts2, char* ws) {
  __shared__ unsigned sBuf[4 * CAP];
  const int lane = threadIdx.x & 63;
  const int wIn = threadIdx.x >> 6;
  const int gw = blockIdx.x * 4 + wIn;              // 0..32767
  const int c = gw >> 13;
  const int qi = (int)(__brev((unsigned)(gw & 8191)) >> 19);  // bit-reversed: load balance
  const int s = c >> 1, b = c & 1;
  const int lq = (s == 0 ? npts1 : npts2)[b];
  if (qi >= lq) return;                             // wave-uniform

  const size_t qo = (size_t)(b * PBUF + qi);
  const float* qx = (s == 0 ? xyz1 : xyz2) + qo * 3;
  const float* qh = (s == 0 ? hsv1 : hsv2) + qo * 3;
  const float* qn = (s == 0 ? normal1 : normal2) + qo * 3;
  const float* qr = (s == 0 ? nres1 : nres2) + qo;
  const float qpx = qx[0], qpy = qx[1], qpz = qx[2];
  const float qh0 = qh[0], qh1 = qh[1], qh2 = qh[2];
  const float qn0 = qn[0], qn1 = qn[1], qn2 = qn[2];
  const float qres = qr[0];

  const float ell = fmaxf(0.015f * (qpz - 10.0f), 0.15f);
  const float ls = ell * ell;
  const float thrF = THR_MULT * ls;
  const float rad = sqrtf(thrF);

  const int* F = (const int*)(ws + OFF_DBSTART) + c * (NBINS + 1);
  const int zlo = binOfZ(qpz - rad), zhi = binOfZ(qpz + rad);
  const int ylo = binOfY(qpy - rad), yhi = binOfY(qpy + rad);
  const int nseg = zhi - zlo + 1;                   // <= 14

  int segS = 0, segLen = 0;
  if (lane < nseg) {
    int zk = zlo + lane;
    segS = F[zk * NYB + ylo];
    segLen = F[zk * NYB + yhi + 1] - segS;          // yhi=31 rolls into next z-bin start: correct
  }
  int cum = segLen;
  #pragma unroll
  for (int o = 1; o < 64; o <<= 1) {
    int n = __shfl_up(cum, o);
    if (lane >= o) cum += n;
  }
  const int L = __shfl(cum, 63);
  const int excl = cum - segLen;

  const float4* dbPos = (const float4*)(ws + OFF_DBPOS) + c * PBUF;
  const float4* dbF1  = (const float4*)(ws + OFF_DBF1) + c * PBUF;
  const float4* dbF2  = (const float4*)(ws + OFF_DBF2) + c * PBUF;

  unsigned* buf = sBuf + wIn * CAP;
  int pos = 0;
  for (int base = 0; base < L; base += 64) {
    int t = base + lane;
    bool in = t < L;
    int tc = min(t, L - 1);
    int kk = 0;                                     // binary search: largest k with excl[k] <= tc
    #pragma unroll
    for (int step = 8; step; step >>= 1) {
      int cnd = kk + step;
      int e = __shfl(excl, cnd & 63);
      if (cnd < nseg && e <= tc) kk = cnd;
    }
    int j = __shfl(segS, kk) + (tc - __shfl(excl, kk));
    float4 p = dbPos[j];
    float dx = p.x - qpx, dy = p.y - qpy, dz = p.z - qpz;
    float d2 = __fmaf_rn(dx, dx, __fmaf_rn(dy, dy, dz * dz));
    bool keep = in && (d2 <= thrF);
    unsigned long long m = __ballot(keep);
    int rank = (int)__popcll(m & ((1ull << lane) - 1ull));
    if (keep) {
      int pidx = pos + rank;
      if (pidx < CAP) buf[pidx] = (__float_as_uint(d2) & D2_MASK) | (unsigned)j;
    }
    pos += (int)__popcll(m);
  }
  pos = min(pos, CAP);

  // select top-KNN survivors; deposit r-th smallest on lane r
  unsigned key = KEY_INF;
  if (pos <= KNN) {
    if (lane < pos) key = buf[lane];                // all survive: selection is identity
  } else if (pos <= 64) {
    unsigned v = (lane < pos) ? buf[lane] : KEY_INF;
    #pragma unroll
    for (int k = 2; k <= 64; k <<= 1) {
      #pragma unroll
      for (int j2 = k >> 1; j2 > 0; j2 >>= 1) {
        unsigned o = __shfl_xor(v, j2);
        bool up = (lane & k) == 0;
        bool lowhalf = (lane & j2) == 0;
        v = (lowhalf == up) ? min(v, o) : max(v, o);
      }
    }
    key = v;                                        // ascending across lanes
  } else {
    unsigned r0 = (lane < pos) ? buf[lane] : KEY_INF;
    unsigned r1 = (lane + 64 < pos) ? buf[lane + 64] : KEY_INF;
    unsigned r2 = (lane + 128 < pos) ? buf[lane + 128] : KEY_INF;
    unsigned r3 = (lane + 192 < pos) ? buf[lane + 192] : KEY_INF;
    { unsigned lo, hi;
      lo = min(r0, r1); hi = max(r0, r1); r0 = lo; r1 = hi;
      lo = min(r2, r3); hi = max(r2, r3); r2 = lo; r3 = hi;
      lo = min(r0, r2); hi = max(r0, r2); r0 = lo; r2 = hi;
      lo = min(r1, r3); hi = max(r1, r3); r1 = lo; r3 = hi;
      lo = min(r1, r2); hi = max(r1, r2); r1 = lo; r2 = hi; }
    unsigned kout = KEY_INF;
    #pragma unroll
    for (int t = 0; t < KNN; ++t) {
      unsigned m0 = r0;
      m0 = min(m0, __shfl_xor(m0, 1));
      m0 = min(m0, __shfl_xor(m0, 2));
      m0 = min(m0, __shfl_xor(m0, 4));
      m0 = min(m0, __shfl_xor(m0, 8));
      m0 = min(m0, __shfl_xor(m0, 16));
      m0 = min(m0, __shfl_xor(m0, 32));
      unsigned long long bal = __ballot(r0 == m0);
      int owner = __ffsll(bal) - 1;                 // keys unique (idx embedded)
      if (lane == owner) { r0 = r1; r1 = r2; r2 = r3; r3 = KEY_INF; }
      if (lane == t) kout = m0;
    }
    key = kout;
  }

  // evaluate: lanes 0..19 each handle one selected neighbor
  float lsum = 0.f;
  if (lane < KNN && key != KEY_INF) {
    int j = (int)(key & IDX_MASK);
    float4 p = dbPos[j];
    float4 f1 = dbF1[j];
    float4 f2 = dbF2[j];
    float dx = p.x - qpx, dy = p.y - qpy, dz = p.z - qpz;
    float d2 = __fmaf_rn(dx, dx, __fmaf_rn(dy, dy, dz * dz));   // exact d2
    float inv_ls = 1.0f / ls;
    float dist_k = __expf(-d2 * inv_ls);
    float c0 = qh0 - f1.x, c1 = qh1 - f1.y, c2 = qh2 - f1.z;
    float cd = sqrtf(__fmaf_rn(c0, c0, __fmaf_rn(c1, c1, c2 * c2)) + 1e-12f);
    float color_k = __expf(cd * -5.0f);
    float alpha = 0.2f / (0.1f + qres + f1.w);
    float nd = __fmaf_rn(qn0, f2.x, __fmaf_rn(qn1, f2.y, qn2 * f2.z));
    float nk = fmaxf(nd * alpha, 0.0f);
    lsum = dist_k * color_k * nk;
  }
  #pragma unroll
  for (int o = 32; o; o >>= 1) lsum += __shfl_down(lsum, o);
  if (lane == 0)
    atomicAdd((float*)(ws + OFF_ACCUM) + (s * 256 + (blockIdx.x & 255)), lsum);
}

// ---------------- K_final: reduce 2x256 cells ----------------
__global__ void k_final(const int* npts1, const int* npts2, const char* ws, float* out) {
  int lane = threadIdx.x;   // 64
  const float* acc = (const float*)(ws + OFF_ACCUM);
  float s1 = acc[lane] + acc[lane + 64] + acc[lane + 128] + acc[lane + 192];
  float s2 = acc[256 + lane] + acc[256 + lane + 64] + acc[256 + lane + 128] + acc[256 + lane + 192];
  #pragma unroll
  for (int o = 32; o; o >>= 1) {
    s1 += __shfl_down(s1, o);
    s2 += __shfl_down(s2, o);
  }
  if (lane == 0) {
    float k1 = s1 / (20.0f * (float)(npts1[0] + npts1[1]));
    float k2 = s2 / (20.0f * (float)(npts2[0] + npts2[1]));
    out[0] = 0.5f * (k1 + k2);
  }
}

extern "C" void kernel_launch(void* const* d_in, const int* in_sizes, int n_in,
                              void* d_out, int out_size, void* d_ws, size_t ws_size,
                              hipStream_t stream) {
  const float* xyz1 = (const float*)d_in[0];
  const float* xyz2 = (const float*)d_in[1];
  const float* hsv1 = (const float*)d_in[2];
  const float* hsv2 = (const float*)d_in[3];
  const float* normal1 = (const float*)d_in[4];
  const float* normal2 = (const float*)d_in[5];
  const float* nres1 = (const float*)d_in[6];
  const float* nres2 = (const float*)d_in[7];
  const float* R12 = (const float*)d_in[8];
  const float* t12 = (const float*)d_in[9];
  const float* R21 = (const float*)d_in[10];
  const float* t21 = (const float*)d_in[11];
  const int* npts1 = (const int*)d_in[12];
  const int* npts2 = (const int*)d_in[13];
  char* ws = (char*)d_ws;
  float* out = (float*)d_out;

  k_build<<<dim3(NCOMBO), dim3(1024), 0, stream>>>(
      xyz1, xyz2, hsv1, hsv2, normal1, normal2, nres1, nres2,
      R12, t12, R21, t21, npts1, npts2, ws);
  k_main<<<dim3(NCOMBO * PBUF / 4), dim3(256), 0, stream>>>(
      xyz1, xyz2, hsv1, hsv2, normal1, normal2, nres1, nres2, npts1, npts2, ws);
  k_final<<<dim3(1), dim3(64), 0, stream>>>(npts1, npts2, ws, out);
}